// Round 1
// baseline (2853.755 us; speedup 1.0000x reference)
//
#include <hip/hip_runtime.h>

typedef unsigned int   uint32;
typedef unsigned short ushort16;

#define NN    50000
#define RR    16
#define BB    8
#define DIN   128
#define DOUT  128
#define NNZ_C 1600000

typedef short  short8  __attribute__((ext_vector_type(8)));
typedef float  floatx4 __attribute__((ext_vector_type(4)));

__device__ __forceinline__ ushort16 f2bf(float f) {
    uint32 u = __float_as_uint(f);
    u += 0x7fffu + ((u >> 16) & 1u);   // round-to-nearest-even
    return (ushort16)(u >> 16);
}

__device__ __forceinline__ float bf2f(ushort16 h) {
    return __uint_as_float(((uint32)h) << 16);
}

// ---------------------------------------------------------------------------
// Kernel 1: Wt[r][j][k] = sum_b comp[r][b] * basis[b][k][j]   (bf16, transposed
// so the GEMM's B-operand fragment reads are contiguous in k)
// ---------------------------------------------------------------------------
__global__ void build_wt_kernel(const float* __restrict__ basis,
                                const float* __restrict__ comp,
                                ushort16* __restrict__ Wt) {
    int idx = blockIdx.x * 256 + threadIdx.x;      // R*DOUT*DIN = 262144 total
    int r = idx >> 14;
    int j = (idx >> 7) & 127;
    int k = idx & 127;
    float s = 0.f;
#pragma unroll
    for (int b = 0; b < BB; ++b)
        s += comp[r * BB + b] * basis[((size_t)b * DIN + k) * DOUT + j];
    Wt[idx] = f2bf(s);
}

// ---------------------------------------------------------------------------
// Kernel 2: FW[r*N + n][j] = sum_k X[n][k] * W_r[k][j]  (bf16 out, MFMA)
// grid: (ceil(N/64), R), block 256 (4 waves, 16 rows each)
// ---------------------------------------------------------------------------
#define WT_LDS_STRIDE 136   // 128 + 8 pad: breaks 16-way bank conflict, keeps 16B align

__global__ __launch_bounds__(256) void gemm_fw_kernel(
        const float* __restrict__ X,
        const ushort16* __restrict__ Wt,
        ushort16* __restrict__ FW) {
    __shared__ __align__(16) ushort16 Wt_lds[128 * WT_LDS_STRIDE];

    const int tid  = threadIdx.x;
    const int wave = tid >> 6;
    const int lane = tid & 63;
    const int m    = lane & 15;
    const int half = lane >> 4;
    const int r    = blockIdx.y;
    const int row_base = blockIdx.x * 64 + wave * 16;

    // stage Wt[r] (128x128 bf16 = 32 KB) into LDS, 16B per thread per iter
    const uint4* wt_g = (const uint4*)(Wt + (size_t)r * DOUT * DIN);
#pragma unroll
    for (int it = 0; it < 8; ++it) {
        int g8 = (it * 256 + tid) * 8;          // element index, multiple of 8
        int j  = g8 >> 7;
        int k  = g8 & 127;
        *(uint4*)&Wt_lds[j * WT_LDS_STRIDE + k] = wt_g[g8 >> 3];
    }
    __syncthreads();

    floatx4 acc[8] = {};

#pragma unroll
    for (int k0 = 0; k0 < 128; k0 += 32) {
        // A fragment: A[m][k] = X[row_base+m][k0 + half*8 + j], j=0..7
        int row  = row_base + m;
        int rowc = row < NN ? row : NN - 1;
        const float* xp = X + (size_t)rowc * DIN + k0 + half * 8;
        float4 xa = *(const float4*)xp;
        float4 xb = *(const float4*)(xp + 4);
        short8 afrag;
        afrag[0] = (short)f2bf(xa.x); afrag[1] = (short)f2bf(xa.y);
        afrag[2] = (short)f2bf(xa.z); afrag[3] = (short)f2bf(xa.w);
        afrag[4] = (short)f2bf(xb.x); afrag[5] = (short)f2bf(xb.y);
        afrag[6] = (short)f2bf(xb.z); afrag[7] = (short)f2bf(xb.w);

#pragma unroll
        for (int t = 0; t < 8; ++t) {
            // B fragment: B[k][n] = W_r[k0+half*8+j][t*16+m] = Wt[t*16+m][k0+half*8+j]
            int j = t * 16 + m;
            short8 bfrag = *(const short8*)&Wt_lds[j * WT_LDS_STRIDE + k0 + half * 8];
            acc[t] = __builtin_amdgcn_mfma_f32_16x16x32_bf16(afrag, bfrag, acc[t], 0, 0, 0);
        }
    }

    // C/D layout: col = lane&15, row = half*4 + reg
#pragma unroll
    for (int t = 0; t < 8; ++t) {
#pragma unroll
        for (int reg = 0; reg < 4; ++reg) {
            int grow = row_base + half * 4 + reg;
            if (grow < NN) {
                int gcol = t * 16 + m;
                FW[((size_t)r * NN + grow) * DOUT + gcol] = f2bf(acc[t][reg]);
            }
        }
    }
}

// ---------------------------------------------------------------------------
// Kernel 3: out[rows[e]] += vals[e] * FW[cols[e]]   (atomic scatter)
// 32 lanes per edge, 4 columns per lane; 8 edges per 256-thread block
// ---------------------------------------------------------------------------
__global__ __launch_bounds__(256) void edge_scatter_kernel(
        const int* __restrict__ rows,
        const int* __restrict__ cols,
        const float* __restrict__ vals,
        const ushort16* __restrict__ FW,
        float* __restrict__ out,
        int nnz) {
    int e = blockIdx.x * 8 + (threadIdx.x >> 5);
    if (e >= nnz) return;
    int sub = threadIdx.x & 31;

    int   row = rows[e];
    int   c   = cols[e];
    float v   = vals[e];

    const uint2 raw = *(const uint2*)(FW + (size_t)c * DOUT + sub * 4);
    float f0 = bf2f((ushort16)(raw.x & 0xffffu));
    float f1 = bf2f((ushort16)(raw.x >> 16));
    float f2 = bf2f((ushort16)(raw.y & 0xffffu));
    float f3 = bf2f((ushort16)(raw.y >> 16));

    float* op = out + (size_t)row * DOUT + sub * 4;
    atomicAdd(op + 0, v * f0);
    atomicAdd(op + 1, v * f1);
    atomicAdd(op + 2, v * f2);
    atomicAdd(op + 3, v * f3);
}

// ---------------------------------------------------------------------------
extern "C" void kernel_launch(void* const* d_in, const int* in_sizes, int n_in,
                              void* d_out, int out_size, void* d_ws, size_t ws_size,
                              hipStream_t stream) {
    const float* X      = (const float*)d_in[0];
    const int*   A_rows = (const int*)d_in[1];
    const int*   A_cols = (const int*)d_in[2];
    const float* A_vals = (const float*)d_in[3];
    const float* basis  = (const float*)d_in[4];   // (B, DIN, DOUT) f32
    const float* comp   = (const float*)d_in[5];   // (R, B) f32
    float* out = (float*)d_out;

    // workspace layout: [0, 512KB) Wt bf16 (R,DOUT,DIN); then FW bf16 (R*N, DOUT)
    ushort16* Wt = (ushort16*)d_ws;
    ushort16* FW = (ushort16*)((char*)d_ws + 512 * 1024);

    // output is accumulated with atomics -> zero it (harness poisons with 0xAA)
    hipMemsetAsync(d_out, 0, (size_t)NN * DOUT * sizeof(float), stream);

    build_wt_kernel<<<(RR * DOUT * DIN) / 256, 256, 0, stream>>>(basis, comp, Wt);

    dim3 g2((NN + 63) / 64, RR);
    gemm_fw_kernel<<<g2, 256, 0, stream>>>(X, Wt, FW);

    edge_scatter_kernel<<<(NNZ_C + 7) / 8, 256, 0, stream>>>(
        A_rows, A_cols, A_vals, FW, out, NNZ_C);
}

// Round 2
// 461.065 us; speedup vs baseline: 6.1895x; 6.1895x over previous
//
#include <hip/hip_runtime.h>

typedef unsigned int   uint32;
typedef unsigned short ushort16;

#define NN    50000
#define RR    16
#define BB    8
#define DIN   128
#define DOUT  128
#define NNZ_C 1600000
#define NB_SCAN 196   // ceil(NN/256)

typedef short  short8  __attribute__((ext_vector_type(8)));
typedef float  floatx4 __attribute__((ext_vector_type(4)));

__device__ __forceinline__ ushort16 f2bf(float f) {
    uint32 u = __float_as_uint(f);
    u += 0x7fffu + ((u >> 16) & 1u);   // round-to-nearest-even
    return (ushort16)(u >> 16);
}

__device__ __forceinline__ float bf2f(ushort16 h) {
    return __uint_as_float(((uint32)h) << 16);
}

// ---------------------------------------------------------------------------
// Kernel 1: Wt[r][j][k] = sum_b comp[r][b] * basis[b][k][j]  (bf16, k-contig)
// ---------------------------------------------------------------------------
__global__ void build_wt_kernel(const float* __restrict__ basis,
                                const float* __restrict__ comp,
                                ushort16* __restrict__ Wt) {
    int idx = blockIdx.x * 256 + threadIdx.x;      // R*DOUT*DIN = 262144 total
    int r = idx >> 14;
    int j = (idx >> 7) & 127;
    int k = idx & 127;
    float s = 0.f;
#pragma unroll
    for (int b = 0; b < BB; ++b)
        s += comp[r * BB + b] * basis[((size_t)b * DIN + k) * DOUT + j];
    Wt[idx] = f2bf(s);
}

// ---------------------------------------------------------------------------
// Kernel 2: FW[r*N + n][j] = sum_k X[n][k] * W_r[k][j]  (bf16 out, MFMA)
// ---------------------------------------------------------------------------
#define WT_LDS_STRIDE 136   // 128 + 8 pad

__global__ __launch_bounds__(256) void gemm_fw_kernel(
        const float* __restrict__ X,
        const ushort16* __restrict__ Wt,
        ushort16* __restrict__ FW) {
    __shared__ __align__(16) ushort16 Wt_lds[128 * WT_LDS_STRIDE];

    const int tid  = threadIdx.x;
    const int wave = tid >> 6;
    const int lane = tid & 63;
    const int m    = lane & 15;
    const int half = lane >> 4;
    const int r    = blockIdx.y;
    const int row_base = blockIdx.x * 64 + wave * 16;

    const uint4* wt_g = (const uint4*)(Wt + (size_t)r * DOUT * DIN);
#pragma unroll
    for (int it = 0; it < 8; ++it) {
        int g8 = (it * 256 + tid) * 8;
        int j  = g8 >> 7;
        int k  = g8 & 127;
        *(uint4*)&Wt_lds[j * WT_LDS_STRIDE + k] = wt_g[g8 >> 3];
    }
    __syncthreads();

    floatx4 acc[8] = {};

#pragma unroll
    for (int k0 = 0; k0 < 128; k0 += 32) {
        int row  = row_base + m;
        int rowc = row < NN ? row : NN - 1;
        const float* xp = X + (size_t)rowc * DIN + k0 + half * 8;
        float4 xa = *(const float4*)xp;
        float4 xb = *(const float4*)(xp + 4);
        short8 afrag;
        afrag[0] = (short)f2bf(xa.x); afrag[1] = (short)f2bf(xa.y);
        afrag[2] = (short)f2bf(xa.z); afrag[3] = (short)f2bf(xa.w);
        afrag[4] = (short)f2bf(xb.x); afrag[5] = (short)f2bf(xb.y);
        afrag[6] = (short)f2bf(xb.z); afrag[7] = (short)f2bf(xb.w);

#pragma unroll
        for (int t = 0; t < 8; ++t) {
            int j = t * 16 + m;
            short8 bfrag = *(const short8*)&Wt_lds[j * WT_LDS_STRIDE + k0 + half * 8];
            acc[t] = __builtin_amdgcn_mfma_f32_16x16x32_bf16(afrag, bfrag, acc[t], 0, 0, 0);
        }
    }

#pragma unroll
    for (int t = 0; t < 8; ++t) {
#pragma unroll
        for (int reg = 0; reg < 4; ++reg) {
            int grow = row_base + half * 4 + reg;
            if (grow < NN) {
                int gcol = t * 16 + m;
                FW[((size_t)r * NN + grow) * DOUT + gcol] = f2bf(acc[t][reg]);
            }
        }
    }
}

// ---------------------------------------------------------------------------
// CSR build: histogram -> 2-level exclusive scan -> bucket
// ---------------------------------------------------------------------------
__global__ void hist_kernel(const int* __restrict__ rows,
                            int* __restrict__ counts, int nnz) {
    int e = blockIdx.x * 256 + threadIdx.x;
    if (e < nnz) atomicAdd(&counts[rows[e]], 1);
}

__global__ void scan1_kernel(const int* __restrict__ counts,
                             int* __restrict__ row_start,
                             int* __restrict__ block_sums) {
    __shared__ int tmp[256];
    int tid = threadIdx.x;
    int gid = blockIdx.x * 256 + tid;
    int v = (gid < NN) ? counts[gid] : 0;
    tmp[tid] = v;
    __syncthreads();
#pragma unroll
    for (int off = 1; off < 256; off <<= 1) {
        int t = (tid >= off) ? tmp[tid - off] : 0;
        __syncthreads();
        tmp[tid] += t;
        __syncthreads();
    }
    if (gid < NN) row_start[gid] = tmp[tid] - v;     // exclusive
    if (tid == 255) block_sums[blockIdx.x] = tmp[255];
}

__global__ void scan2_kernel(const int* __restrict__ block_sums,
                             int* __restrict__ block_offs) {
    __shared__ int tmp[256];
    int tid = threadIdx.x;
    int v = (tid < NB_SCAN) ? block_sums[tid] : 0;
    tmp[tid] = v;
    __syncthreads();
#pragma unroll
    for (int off = 1; off < 256; off <<= 1) {
        int t = (tid >= off) ? tmp[tid - off] : 0;
        __syncthreads();
        tmp[tid] += t;
        __syncthreads();
    }
    if (tid < NB_SCAN) block_offs[tid] = tmp[tid] - v;  // exclusive
}

__global__ void scan3_kernel(int* __restrict__ row_start,
                             const int* __restrict__ block_offs) {
    int gid = blockIdx.x * 256 + threadIdx.x;
    if (gid < NN) row_start[gid] += block_offs[blockIdx.x];
    if (gid == 0) row_start[NN] = NNZ_C;
}

__global__ void bucket_kernel(const int* __restrict__ rows,
                              const int* __restrict__ cols,
                              const float* __restrict__ vals,
                              const int* __restrict__ row_start,
                              int* __restrict__ cursor,
                              uint2* __restrict__ es, int nnz) {
    int e = blockIdx.x * 256 + threadIdx.x;
    if (e >= nnz) return;
    int row = rows[e];
    int pos = row_start[row] + atomicAdd(&cursor[row], 1);
    es[pos] = make_uint2((uint32)cols[e], __float_as_uint(vals[e]));
}

// ---------------------------------------------------------------------------
// Row accumulate: one wave per row, lane = column pair; no atomics.
// ---------------------------------------------------------------------------
__global__ __launch_bounds__(256) void row_accum_kernel(
        const uint2* __restrict__ es,
        const int* __restrict__ row_start,
        const ushort16* __restrict__ FW,
        float* __restrict__ out) {
    int row  = (blockIdx.x * 256 + threadIdx.x) >> 6;
    int lane = threadIdx.x & 63;
    if (row >= NN) return;

    int beg = row_start[row];
    int end = row_start[row + 1];

    float a0 = 0.f, a1 = 0.f;
    int e = beg;
    for (; e + 1 < end; e += 2) {
        uint2 e0 = es[e];
        uint2 e1 = es[e + 1];
        uint32 p0 = *(const uint32*)(FW + (size_t)e0.x * DOUT + lane * 2);
        uint32 p1 = *(const uint32*)(FW + (size_t)e1.x * DOUT + lane * 2);
        float v0 = __uint_as_float(e0.y);
        float v1 = __uint_as_float(e1.y);
        a0 += v0 * bf2f((ushort16)(p0 & 0xffffu));
        a1 += v0 * bf2f((ushort16)(p0 >> 16));
        a0 += v1 * bf2f((ushort16)(p1 & 0xffffu));
        a1 += v1 * bf2f((ushort16)(p1 >> 16));
    }
    if (e < end) {
        uint2 e0 = es[e];
        uint32 p0 = *(const uint32*)(FW + (size_t)e0.x * DOUT + lane * 2);
        float v0 = __uint_as_float(e0.y);
        a0 += v0 * bf2f((ushort16)(p0 & 0xffffu));
        a1 += v0 * bf2f((ushort16)(p0 >> 16));
    }

    *(float2*)(out + (size_t)row * DOUT + lane * 2) = make_float2(a0, a1);
}

// ---------------------------------------------------------------------------
extern "C" void kernel_launch(void* const* d_in, const int* in_sizes, int n_in,
                              void* d_out, int out_size, void* d_ws, size_t ws_size,
                              hipStream_t stream) {
    const float* X      = (const float*)d_in[0];
    const int*   A_rows = (const int*)d_in[1];
    const int*   A_cols = (const int*)d_in[2];
    const float* A_vals = (const float*)d_in[3];
    const float* basis  = (const float*)d_in[4];
    const float* comp   = (const float*)d_in[5];
    float* out = (float*)d_out;

    // workspace layout
    char* ws = (char*)d_ws;
    ushort16* Wt         = (ushort16*)(ws + 0);               //   512 KB
    ushort16* FW         = (ushort16*)(ws + 524288);          // 204.8 MB
    int*      row_start  = (int*)(ws + 205324288);            // (N+1) ints
    int*      counts     = (int*)(ws + 205529088);            // N ints
    int*      cursor     = (int*)(ws + 205733888);            // N ints
    int*      block_sums = (int*)(ws + 205938688);            // 256 ints
    int*      block_offs = (int*)(ws + 205942784);            // 256 ints
    uint2*    es         = (uint2*)(ws + 205946880);          // 12.8 MB

    hipMemsetAsync(counts, 0, NN * sizeof(int), stream);
    hipMemsetAsync(cursor, 0, NN * sizeof(int), stream);

    build_wt_kernel<<<(RR * DOUT * DIN) / 256, 256, 0, stream>>>(basis, comp, Wt);

    dim3 g2((NN + 63) / 64, RR);
    gemm_fw_kernel<<<g2, 256, 0, stream>>>(X, Wt, FW);

    int nb_e = (NNZ_C + 255) / 256;
    hist_kernel<<<nb_e, 256, 0, stream>>>(A_rows, counts, NNZ_C);
    scan1_kernel<<<NB_SCAN, 256, 0, stream>>>(counts, row_start, block_sums);
    scan2_kernel<<<1, 256, 0, stream>>>(block_sums, block_offs);
    scan3_kernel<<<NB_SCAN, 256, 0, stream>>>(row_start, block_offs);
    bucket_kernel<<<nb_e, 256, 0, stream>>>(A_rows, A_cols, A_vals,
                                            row_start, cursor, es, NNZ_C);

    row_accum_kernel<<<(NN * 64 + 255) / 256, 256, 0, stream>>>(
        es, row_start, FW, out);
}